// Round 2
// baseline (656.631 us; speedup 1.0000x reference)
//
#include <hip/hip_runtime.h>
#include <hip/hip_fp16.h>
#include <math.h>

#define NATOMS 25000
#define NPAIRS 400000
#define CAP 96
#define XSIZE (NATOMS * 32 * 9)   // 7,200,000 floats; radial follows at this offset
#define TWO_PI 6.28318530717958647692f
#define PPW 8   // pairs per sub-half per k_pair wave iteration group
#define WPB 8   // waves (=atoms) per k_atom2 block

__device__ __forceinline__ float silu_f(float x) { return x / (1.0f + expf(-x)); }

// ---------------- K0: EW = emb_table @ w_zij halves ----------------
// EW[tab*3200 + z*32 + f]: tab 0 -> w_zij cols 0..31 (atom i), tab 1 -> cols 32..63 (atom j)
__global__ void k_ew(const float* __restrict__ emb, const float* __restrict__ wz,
                     float* __restrict__ EW) {
    int t = blockIdx.x * 256 + threadIdx.x;
    if (t >= 2 * 100 * 32) return;
    int tab = t / 3200;
    int rem = t - tab * 3200;
    int z = rem >> 5;
    int f = rem & 31;
    const float* e = emb + z * 32;
    const float* w = wz + f * 64 + tab * 32;
    float acc = 0.f;
#pragma unroll
    for (int k = 0; k < 32; k++) acc += e[k] * w[k];
    EW[t] = acc;
}

// ---------------- K1: bucket pairs by segment atom ----------------
__global__ void k_build(const int* __restrict__ pidx, int* __restrict__ counts,
                        int* __restrict__ lists) {
    int p = blockIdx.x * 256 + threadIdx.x;
    if (p >= NPAIRS) return;
    int i = pidx[p];
    int slot = atomicAdd(&counts[i], 1);
    if (slot < CAP) lists[i * CAP + slot] = p;
}

// ---------------- K2: pair-major coefficient kernel (fully coalesced) ----------------
// wave layout: lane = f(0..31) x sub(0..1); each sub handles one pair per iteration.
// Per pair computes radial (written to output) and aI,aA,aS coefs -> fp16 workspace.
__global__ __launch_bounds__(256, 4) void k_pair(
    const int* __restrict__ anum, const int* __restrict__ pidx,
    const float* __restrict__ r_ij, const float* __restrict__ d_ij,
    const float* __restrict__ EW, const float* __restrict__ b_zij,
    const float* __restrict__ w_I, const float* __restrict__ b_I,
    const float* __restrict__ w_A, const float* __restrict__ b_A,
    const float* __restrict__ w_S, const float* __restrict__ b_S,
    __half2* __restrict__ coefIA, __half* __restrict__ coefS,
    float* __restrict__ rhat4, float* __restrict__ out_rad) {
    __shared__ float ewl[6400];
    for (int i = threadIdx.x; i < 6400; i += 256) ewl[i] = EW[i];

    const int tid = threadIdx.x;
    const int lane = tid & 63;
    const int wave = tid >> 6;
    const int f = lane & 31;
    const int sub = lane >> 5;
    const int sh = sub << 5;

    // per-lane register copies of radial-weight rows (feature f) — L1-resident loads
    float wIr[32], wAr[32], wSr[32];
#pragma unroll
    for (int k = 0; k < 32; k++) {
        wIr[k] = w_I[f * 32 + k];
        wAr[k] = w_A[f * 32 + k];
        wSr[k] = w_S[f * 32 + k];
    }
    const float bIv = b_I[f], bAv = b_A[f], bSv = b_S[f], bzv = b_zij[f];

    const float start = 0.006737946999085467f;          // exp(-5)
    const float step = (1.0f - start) * (1.0f / 31.0f);
    const float tmp = 0.0625f * (1.0f - start);
    const float bconst = 1.0f / (tmp * tmp);
    const float center = start + (float)f * step;

    __syncthreads();

    const int base_p = (blockIdx.x * 4 + wave) * (2 * PPW);

    for (int it = 0; it < PPW; it++) {
        const int p = base_p + it * 2 + sub;
        float d = d_ij[p];                               // broadcast within sub
        float rx = r_ij[3 * p], ry = r_ij[3 * p + 1], rz = r_ij[3 * p + 2];
        float invd = 1.0f / d;
        rx *= invd; ry *= invd; rz *= invd;
        float rcut = (d < 0.5f) ? 0.5f * (cosf(d * TWO_PI) + 1.0f) : 0.0f;
        float ee = expf(-10.0f * d);
        float diff = ee - center;
        float radf = expf(-bconst * diff * diff) * rcut;
        out_rad[(long)p * 32 + f] = radf;                // coalesced 128B/sub
        if (f < 3) rhat4[p * 4 + f] = (f == 0) ? rx : ((f == 1) ? ry : rz);

        int ai = pidx[p], aj = pidx[NPAIRS + p];
        int zi = anum[ai], zj = anum[aj];                // L2-resident gathers
        float zf = ewl[zi * 32 + f] + ewl[3200 + zj * 32 + f] + bzv;
        float C = rcut * zf;

        float fIv = bIv, fAv = bAv, fSv = bSv;
#pragma unroll
        for (int k = 0; k < 32; k++) {
            float rk = __shfl(radf, sh + k, 64);         // broadcast radial_k of my pair
            fIv += rk * wIr[k];
            fAv += rk * wAr[k];
            fSv += rk * wSr[k];
        }
        coefIA[(long)p * 32 + f] = __floats2half2_rn(fIv * C, fAv * C);  // coalesced
        coefS[(long)p * 32 + f] = __float2half_rn(fSv * C);
    }
}

// ---------------- K3: atom-major gather + fused epilogue ----------------
// 512 threads = 8 waves = 8 atoms/block; all epilogue LDS is per-wave private
// (wave-lockstep ordering -> no __syncthreads after weight staging).
__global__ __launch_bounds__(512) void k_atom2(
    const __half2* __restrict__ coefIA, const __half* __restrict__ coefS,
    const float* __restrict__ rhat4,
    const float* __restrict__ w_t0, const float* __restrict__ w_t1,
    const float* __restrict__ w_t2,
    const float* __restrict__ w_s1, const float* __restrict__ b_s1,
    const float* __restrict__ w_s2, const float* __restrict__ b_s2,
    const float* __restrict__ ln_w, const float* __restrict__ ln_b,
    const int* __restrict__ counts, const int* __restrict__ lists,
    float* __restrict__ out) {
    __shared__ float ws1t[32 * 65];       // [f][o]  (pad keeps staging writes conflict-free)
    __shared__ float ws2t[64 * 97];       // [k][o]
    __shared__ float wt0t[32 * 33];       // [f][g]
    __shared__ float wt1t[32 * 33];
    __shared__ float wt2t[32 * 33];
    __shared__ float h_st[WPB][32];
    __shared__ float h1_st[WPB][64];
    __shared__ float h2_st[WPB][96];
    __shared__ float vals_st[WPB][320];   // 10 comps x 32f; reused as X staging (288)

    const int tid = threadIdx.x;
    for (int i = tid; i < 64 * 32; i += 512) { int o = i >> 5, ff = i & 31; ws1t[ff * 65 + o] = w_s1[i]; }
    for (int i = tid; i < 96 * 64; i += 512) { int o = i >> 6, k = i & 63; ws2t[k * 97 + o] = w_s2[i]; }
    for (int i = tid; i < 32 * 32; i += 512) {
        int g = i >> 5, ff = i & 31;
        wt0t[ff * 33 + g] = w_t0[i];
        wt1t[ff * 33 + g] = w_t1[i];
        wt2t[ff * 33 + g] = w_t2[i];
    }
    __syncthreads();

    const int wave = tid >> 6;
    const int lane = tid & 63;
    const int f = lane & 31;
    const int sub = lane >> 5;
    const int atom = blockIdx.x * WPB + wave;

    float sI = 0.f, vA0 = 0.f, vA1 = 0.f, vA2 = 0.f;
    float Sxx = 0.f, Sxy = 0.f, Sxz = 0.f, Syy = 0.f, Syz = 0.f, Szz = 0.f;

    int cnt = counts[atom];
    if (cnt > CAP) cnt = CAP;
    const int* __restrict__ mylist = lists + atom * CAP;

    int p_next = (cnt > 0) ? mylist[(sub < cnt) ? sub : (cnt - 1)] : 0;
    for (int t0 = 0; t0 < cnt; t0 += 2) {
        const int idx = t0 + sub;
        const bool valid = idx < cnt;
        const int p = p_next;
        int idx2 = t0 + 2 + sub;
        if (idx2 > cnt - 1) idx2 = cnt - 1;
        p_next = mylist[idx2];                            // prefetch next iteration's p

        float2 ia = __half22float2(coefIA[(long)p * 32 + f]);
        float aS = __half2float(coefS[(long)p * 32 + f]);
        float4 rh = *(const float4*)(rhat4 + (long)p * 4);
        if (valid) {
            float aI = ia.x, aA = ia.y;
            sI += aI;
            vA0 += aA * rh.x; vA1 += aA * rh.y; vA2 += aA * rh.z;
            Sxx += aS * (rh.x * rh.x - (1.0f / 3.0f));
            Sxy += aS * (rh.x * rh.y);
            Sxz += aS * (rh.x * rh.z);
            Syy += aS * (rh.y * rh.y - (1.0f / 3.0f));
            Syz += aS * (rh.y * rh.z);
            Szz += aS * (rh.z * rh.z - (1.0f / 3.0f));
        }
    }
    // combine the two sub-halves
    sI += __shfl_xor(sI, 32, 64);
    vA0 += __shfl_xor(vA0, 32, 64);
    vA1 += __shfl_xor(vA1, 32, 64);
    vA2 += __shfl_xor(vA2, 32, 64);
    Sxx += __shfl_xor(Sxx, 32, 64);
    Sxy += __shfl_xor(Sxy, 32, 64);
    Sxz += __shfl_xor(Sxz, 32, 64);
    Syy += __shfl_xor(Syy, 32, 64);
    Syz += __shfl_xor(Syz, 32, 64);
    Szz += __shfl_xor(Szz, 32, 64);

    // norm2 of I+A+S for feature f
    float M00 = sI + Sxx, M01 = -vA2 + Sxy, M02 = vA1 + Sxz;
    float M10 = vA2 + Sxy, M11 = sI + Syy, M12 = -vA0 + Syz;
    float M20 = -vA1 + Sxz, M21 = vA0 + Syz, M22 = sI + Szz;
    float norm2 = M00 * M00 + M01 * M01 + M02 * M02 + M10 * M10 + M11 * M11 +
                  M12 * M12 + M20 * M20 + M21 * M21 + M22 * M22;

    // LayerNorm over 32 features (each f present in both subs -> /64)
    float mu = norm2;
#pragma unroll
    for (int m = 32; m >= 1; m >>= 1) mu += __shfl_xor(mu, m, 64);
    mu *= (1.0f / 64.0f);
    float dd = norm2 - mu;
    float vv = dd * dd;
#pragma unroll
    for (int m = 32; m >= 1; m >>= 1) vv += __shfl_xor(vv, m, 64);
    vv *= (1.0f / 64.0f);
    float h = dd * rsqrtf(vv + 1e-5f) * ln_w[f] + ln_b[f];
    if (sub == 0) h_st[wave][f] = h;

    // MLP1: 64 outputs, one per lane (same-wave LDS, lockstep-ordered)
    {
        float acc = b_s1[lane];
#pragma unroll
        for (int k = 0; k < 32; k++) acc += h_st[wave][k] * ws1t[k * 65 + lane];
        h1_st[wave][lane] = silu_f(acc);
    }

    // MLP2: 96 outputs
    {
        float acc = b_s2[lane];
        float acc2 = (lane < 32) ? b_s2[64 + lane] : 0.f;
#pragma unroll
        for (int k = 0; k < 64; k++) {
            float hk = h1_st[wave][k];
            acc += hk * ws2t[k * 97 + lane];
            if (lane < 32) acc2 += hk * ws2t[k * 97 + 64 + lane];
        }
        h2_st[wave][lane] = silu_f(acc);
        if (lane < 32) h2_st[wave][64 + lane] = silu_f(acc2);
    }

    // stage per-f tensor components for channel mixing
    if (sub == 0) {
        vals_st[wave][0 * 32 + f] = sI;
        vals_st[wave][1 * 32 + f] = vA0;
        vals_st[wave][2 * 32 + f] = vA1;
        vals_st[wave][3 * 32 + f] = vA2;
        vals_st[wave][4 * 32 + f] = Sxx;
        vals_st[wave][5 * 32 + f] = Sxy;
        vals_st[wave][6 * 32 + f] = Sxz;
        vals_st[wave][7 * 32 + f] = Syy;
        vals_st[wave][8 * 32 + f] = Syz;
        vals_st[wave][9 * 32 + f] = Szz;
    }

    // channel mixing + combine with s3; output staged back into vals_st (reads precede writes)
    {
        const int g = f;
        float mI = 0.f, mA0 = 0.f, mA1 = 0.f, mA2 = 0.f;
        float mSxx = 0.f, mSxy = 0.f, mSxz = 0.f, mSyy = 0.f, mSyz = 0.f, mSzz = 0.f;
        const float* V = vals_st[wave];
#pragma unroll 8
        for (int ff = 0; ff < 32; ff++) {
            float w0 = wt0t[ff * 33 + g];
            float w1 = wt1t[ff * 33 + g];
            float w2 = wt2t[ff * 33 + g];
            mI += w0 * V[ff];
            mA0 += w1 * V[32 + ff];
            mA1 += w1 * V[64 + ff];
            mA2 += w1 * V[96 + ff];
            mSxx += w2 * V[128 + ff];
            mSxy += w2 * V[160 + ff];
            mSxz += w2 * V[192 + ff];
            mSyy += w2 * V[224 + ff];
            mSyz += w2 * V[256 + ff];
            mSzz += w2 * V[288 + ff];
        }
        float s0 = h2_st[wave][g * 3 + 0];
        float s1 = h2_st[wave][g * 3 + 1];
        float s2 = h2_st[wave][g * 3 + 2];
        float* X = vals_st[wave];
        if (sub == 0) {
            X[g * 9 + 0] = s0 * mI + s2 * mSxx;
            X[g * 9 + 1] = -s1 * mA2 + s2 * mSxy;
            X[g * 9 + 2] = s1 * mA1 + s2 * mSxz;
            X[g * 9 + 3] = s1 * mA2 + s2 * mSxy;
            X[g * 9 + 4] = s0 * mI + s2 * mSyy;
        } else {
            X[g * 9 + 5] = -s1 * mA0 + s2 * mSyz;
            X[g * 9 + 6] = -s1 * mA1 + s2 * mSxz;
            X[g * 9 + 7] = s1 * mA0 + s2 * mSyz;
            X[g * 9 + 8] = s0 * mI + s2 * mSzz;
        }
    }

    // coalesced X write: 288 contiguous floats per atom
    {
        float* dst = out + (long)atom * 288;
        const float* xs = vals_st[wave];
#pragma unroll
        for (int c = 0; c < 5; c++) {
            int i = lane + c * 64;
            if (i < 288) dst[i] = xs[i];
        }
    }
}

extern "C" void kernel_launch(void* const* d_in, const int* in_sizes, int n_in,
                              void* d_out, int out_size, void* d_ws, size_t ws_size,
                              hipStream_t stream) {
    const int* anum = (const int*)d_in[0];
    const int* pidx = (const int*)d_in[1];
    const float* r_ij = (const float*)d_in[2];
    const float* d_ijp = (const float*)d_in[3];
    const float* emb = (const float*)d_in[4];
    const float* w_zij = (const float*)d_in[5];
    const float* b_zij = (const float*)d_in[6];
    const float* w_I = (const float*)d_in[7];
    const float* b_I = (const float*)d_in[8];
    const float* w_A = (const float*)d_in[9];
    const float* b_A = (const float*)d_in[10];
    const float* w_S = (const float*)d_in[11];
    const float* b_S = (const float*)d_in[12];
    const float* w_t0 = (const float*)d_in[13];
    const float* w_t1 = (const float*)d_in[14];
    const float* w_t2 = (const float*)d_in[15];
    const float* w_s1 = (const float*)d_in[16];
    const float* b_s1 = (const float*)d_in[17];
    const float* w_s2 = (const float*)d_in[18];
    const float* b_s2 = (const float*)d_in[19];
    const float* ln_w = (const float*)d_in[20];
    const float* ln_b = (const float*)d_in[21];
    float* out = (float*)d_out;

    // workspace layout (~93 MB)
    float* EW = (float*)d_ws;                              // 6400 floats
    int* counts = (int*)(EW + 6400);                       // 25000 ints
    int* lists = counts + NATOMS;                          // 2.4M ints
    float* rhat4 = (float*)(lists + NATOMS * CAP);         // 1.6M floats
    __half2* coefIA = (__half2*)(rhat4 + (size_t)NPAIRS * 4);  // 12.8M half2
    __half* coefS = (__half*)(coefIA + (size_t)NPAIRS * 32);   // 12.8M half

    hipMemsetAsync(counts, 0, NATOMS * sizeof(int), stream);
    k_ew<<<25, 256, 0, stream>>>(emb, w_zij, EW);
    k_build<<<(NPAIRS + 255) / 256, 256, 0, stream>>>(pidx, counts, lists);
    k_pair<<<NPAIRS / (8 * PPW), 256, 0, stream>>>(anum, pidx, r_ij, d_ijp, EW, b_zij,
                                                   w_I, b_I, w_A, b_A, w_S, b_S,
                                                   coefIA, coefS, rhat4, out + XSIZE);
    k_atom2<<<NATOMS / WPB, 512, 0, stream>>>(coefIA, coefS, rhat4,
                                              w_t0, w_t1, w_t2, w_s1, b_s1,
                                              w_s2, b_s2, ln_w, ln_b,
                                              counts, lists, out);
}

// Round 3
// 567.455 us; speedup vs baseline: 1.1571x; 1.1571x over previous
//
#include <hip/hip_runtime.h>
#include <hip/hip_fp16.h>
#include <math.h>

#define NATOMS 25000
#define NPAIRS 400000
#define XSIZE (NATOMS * 32 * 9)   // 7,200,000 floats; radial output follows
#define TWO_PI 6.28318530717958647692f
#define WPB 8    // atoms (waves) per k_atom2 block

__device__ __forceinline__ float silu_f(float x) { return x / (1.0f + expf(-x)); }

// ---------------- K0: EW = emb_table @ w_zij halves ----------------
// EW[tab*3200 + z*32 + f]: tab 0 -> w_zij cols 0..31 (atom i), tab 1 -> cols 32..63 (atom j)
__global__ void k_ew(const float* __restrict__ emb, const float* __restrict__ wz,
                     float* __restrict__ EW) {
    int t = blockIdx.x * 256 + threadIdx.x;
    if (t >= 2 * 100 * 32) return;
    int tab = t / 3200;
    int rem = t - tab * 3200;
    int z = rem >> 5;
    int f = rem & 31;
    const float* e = emb + z * 32;
    const float* w = wz + f * 64 + tab * 32;
    float acc = 0.f;
#pragma unroll
    for (int k = 0; k < 32; k++) acc += e[k] * w[k];
    EW[t] = acc;
}

// ---------------- K1: per-atom pair counts ----------------
__global__ void k_count(const int* __restrict__ pidx, int* __restrict__ counts) {
    int p = blockIdx.x * 256 + threadIdx.x;
    if (p >= NPAIRS) return;
    atomicAdd(&counts[pidx[p]], 1);
}

// ---------------- K2: exclusive scan of counts -> offsets (single block) ----------------
__global__ __launch_bounds__(1024) void k_scan(const int* __restrict__ counts,
                                               int* __restrict__ offsets) {
    __shared__ int part[1024];
    const int t = threadIdx.x;
    const int base = t * 25;  // 1024*25 = 25600 >= NATOMS
    int mysum = 0;
    for (int i = 0; i < 25; i++) {
        int idx = base + i;
        mysum += (idx < NATOMS) ? counts[idx] : 0;
    }
    part[t] = mysum;
    __syncthreads();
    for (int off = 1; off < 1024; off <<= 1) {
        int v = (t >= off) ? part[t - off] : 0;
        __syncthreads();
        part[t] += v;
        __syncthreads();
    }
    int excl = part[t] - mysum;
    for (int i = 0; i < 25; i++) {
        int idx = base + i;
        if (idx < NATOMS) {
            offsets[idx] = excl;
            excl += counts[idx];
        }
    }
    if (t == 1023) offsets[NATOMS] = part[1023];
}

// ---------------- K3: compact pair list (atom-sorted) + packed species ----------------
__global__ void k_fill(const int* __restrict__ pidx, const int* __restrict__ anum,
                       const int* __restrict__ offsets, int* __restrict__ cursor,
                       int* __restrict__ qlist, int* __restrict__ zpk) {
    int p = blockIdx.x * 256 + threadIdx.x;
    if (p >= NPAIRS) return;
    int a = pidx[p];
    int aj = pidx[NPAIRS + p];
    int j = atomicAdd(&cursor[a], 1);
    int slot = offsets[a] + j;
    qlist[slot] = p;
    zpk[slot] = (anum[a] << 16) | anum[aj];
}

// ---------------- K4: radial output, pair-ordered, fully coalesced ----------------
__global__ void k_rad(const float* __restrict__ d_ij, float* __restrict__ out_rad) {
    int gid = blockIdx.x * 256 + threadIdx.x;
    if (gid >= NPAIRS * 32) return;
    int p = gid >> 5;
    int f = gid & 31;
    const float start = 0.006737946999085467f;          // exp(-5)
    const float step = (1.0f - start) * (1.0f / 31.0f);
    const float tmp = 0.0625f * (1.0f - start);
    const float bconst = 1.0f / (tmp * tmp);
    const float center = start + (float)f * step;
    float d = d_ij[p];
    float rcut = (d < 0.5f) ? 0.5f * (cosf(d * TWO_PI) + 1.0f) : 0.0f;
    float ee = expf(-10.0f * d);
    float diff = ee - center;
    out_rad[gid] = expf(-bconst * diff * diff) * rcut;
}

// ---------------- K5: slot-ordered coefficient kernel ----------------
// wave: lane = f(0..31) x sub(0..1); 16 slots per wave (8 iters x 2 subs).
// Writes coefIA/coefS/rhatS in slot (atom-sorted) order -> k_atom2 reads sequentially.
__global__ __launch_bounds__(256) void k_pair(
    const int* __restrict__ qlist, const int* __restrict__ zpk,
    const float* __restrict__ r_ij, const float* __restrict__ d_ij,
    const float* __restrict__ EW, const float* __restrict__ b_zij,
    const float* __restrict__ w_I, const float* __restrict__ b_I,
    const float* __restrict__ w_A, const float* __restrict__ b_A,
    const float* __restrict__ w_S, const float* __restrict__ b_S,
    __half2* __restrict__ coefIA, __half* __restrict__ coefS,
    float* __restrict__ rhatS) {
    __shared__ float ewl[6400];
    for (int i = threadIdx.x; i < 6400; i += 256) ewl[i] = EW[i];

    const int tid = threadIdx.x;
    const int lane = tid & 63;
    const int wave = tid >> 6;
    const int f = lane & 31;
    const int sub = lane >> 5;
    const int sh = sub << 5;

    // per-lane register copies of radial-weight rows (feature f).
    // NOTE: no min-occupancy launch bound — these MUST stay in VGPRs (round-2
    // spilled them at VGPR=64 -> 600 MB of scratch traffic).
    float wIr[32], wAr[32], wSr[32];
#pragma unroll
    for (int k = 0; k < 32; k++) {
        wIr[k] = w_I[f * 32 + k];
        wAr[k] = w_A[f * 32 + k];
        wSr[k] = w_S[f * 32 + k];
    }
    const float bIv = b_I[f], bAv = b_A[f], bSv = b_S[f], bzv = b_zij[f];

    const float start = 0.006737946999085467f;
    const float step = (1.0f - start) * (1.0f / 31.0f);
    const float tmp = 0.0625f * (1.0f - start);
    const float bconst = 1.0f / (tmp * tmp);
    const float center = start + (float)f * step;

    __syncthreads();

    const int wave_base = (blockIdx.x * 4 + wave) * 16;
    const int qv = qlist[wave_base + (lane & 15)];  // 16 slots' pair ids, lanes replicated
    const int zv = zpk[wave_base + (lane & 15)];

    int p = __shfl(qv, sub, 64);
    float d = d_ij[p];
    float rx = r_ij[3 * p], ry = r_ij[3 * p + 1], rz = r_ij[3 * p + 2];

#pragma unroll
    for (int it = 0; it < 8; it++) {
        // prefetch next iteration's gathers (off the critical path)
        int pn = p;
        float dn = d, rxn = rx, ryn = ry, rzn = rz;
        if (it < 7) {
            pn = __shfl(qv, it * 2 + 2 + sub, 64);
            dn = d_ij[pn];
            rxn = r_ij[3 * pn];
            ryn = r_ij[3 * pn + 1];
            rzn = r_ij[3 * pn + 2];
        }

        float invd = 1.0f / d;
        float hx = rx * invd, hy = ry * invd, hz = rz * invd;
        float rcut = (d < 0.5f) ? 0.5f * (cosf(d * TWO_PI) + 1.0f) : 0.0f;
        float ee = expf(-10.0f * d);
        float diff = ee - center;
        float radf = expf(-bconst * diff * diff) * rcut;

        int zij = __shfl(zv, it * 2 + sub, 64);
        float zf = ewl[(zij >> 16) * 32 + f] + ewl[3200 + (zij & 0xffff) * 32 + f] + bzv;
        float C = rcut * zf;

        float fIv = bIv, fAv = bAv, fSv = bSv;
#pragma unroll
        for (int k = 0; k < 32; k++) {
            float rk = __shfl(radf, sh + k, 64);
            fIv += rk * wIr[k];
            fAv += rk * wAr[k];
            fSv += rk * wSr[k];
        }

        long s = wave_base + it * 2 + sub;
        coefIA[s * 32 + f] = __floats2half2_rn(fIv * C, fAv * C);  // 256B/wave, slot-seq
        coefS[s * 32 + f] = __float2half_rn(fSv * C);              // 128B/wave
        if (f == 0) {
            float4 v = make_float4(hx, hy, hz, 0.f);
            *(float4*)(rhatS + s * 4) = v;
        }

        p = pn; d = dn; rx = rxn; ry = ryn; rz = rzn;
    }
}

// ---------------- K6: atom-major sequential accumulate + fused epilogue ----------------
// 512 threads = 8 waves = 8 atoms/block; epilogue LDS per-wave private (no barriers
// after weight staging). All coef reads are sequential within the atom's segment.
__global__ __launch_bounds__(512) void k_atom2(
    const __half2* __restrict__ coefIA, const __half* __restrict__ coefS,
    const float* __restrict__ rhatS, const int* __restrict__ offsets,
    const float* __restrict__ w_t0, const float* __restrict__ w_t1,
    const float* __restrict__ w_t2,
    const float* __restrict__ w_s1, const float* __restrict__ b_s1,
    const float* __restrict__ w_s2, const float* __restrict__ b_s2,
    const float* __restrict__ ln_w, const float* __restrict__ ln_b,
    float* __restrict__ out) {
    __shared__ float ws1t[32 * 65];
    __shared__ float ws2t[64 * 97];
    __shared__ float wt0t[32 * 33];
    __shared__ float wt1t[32 * 33];
    __shared__ float wt2t[32 * 33];
    __shared__ float h_st[WPB][32];
    __shared__ float h1_st[WPB][64];
    __shared__ float h2_st[WPB][96];
    __shared__ float vals_st[WPB][320];   // 10 comps x 32f; reused as X staging

    const int tid = threadIdx.x;
    for (int i = tid; i < 64 * 32; i += 512) { int o = i >> 5, ff = i & 31; ws1t[ff * 65 + o] = w_s1[i]; }
    for (int i = tid; i < 96 * 64; i += 512) { int o = i >> 6, k = i & 63; ws2t[k * 97 + o] = w_s2[i]; }
    for (int i = tid; i < 32 * 32; i += 512) {
        int g = i >> 5, ff = i & 31;
        wt0t[ff * 33 + g] = w_t0[i];
        wt1t[ff * 33 + g] = w_t1[i];
        wt2t[ff * 33 + g] = w_t2[i];
    }
    __syncthreads();

    const int wave = tid >> 6;
    const int lane = tid & 63;
    const int f = lane & 31;
    const int sub = lane >> 5;
    const int atom = blockIdx.x * WPB + wave;

    float sI = 0.f, vA0 = 0.f, vA1 = 0.f, vA2 = 0.f;
    float Sxx = 0.f, Sxy = 0.f, Sxz = 0.f, Syy = 0.f, Syz = 0.f, Szz = 0.f;

    const int start = offsets[atom];
    const int cnt = offsets[atom + 1] - start;

    for (int t0 = 0; t0 < cnt; t0 += 2) {
        const int idx = t0 + sub;
        const bool valid = idx < cnt;
        const long s = start + (valid ? idx : 0);
        float2 ia = __half22float2(coefIA[s * 32 + f]);   // 256B/wave, sequential
        float aS = __half2float(coefS[s * 32 + f]);
        float4 rh = *(const float4*)(rhatS + s * 4);
        if (valid) {
            float aI = ia.x, aA = ia.y;
            sI += aI;
            vA0 += aA * rh.x; vA1 += aA * rh.y; vA2 += aA * rh.z;
            Sxx += aS * (rh.x * rh.x - (1.0f / 3.0f));
            Sxy += aS * (rh.x * rh.y);
            Sxz += aS * (rh.x * rh.z);
            Syy += aS * (rh.y * rh.y - (1.0f / 3.0f));
            Syz += aS * (rh.y * rh.z);
            Szz += aS * (rh.z * rh.z - (1.0f / 3.0f));
        }
    }
    // combine sub-halves
    sI += __shfl_xor(sI, 32, 64);
    vA0 += __shfl_xor(vA0, 32, 64);
    vA1 += __shfl_xor(vA1, 32, 64);
    vA2 += __shfl_xor(vA2, 32, 64);
    Sxx += __shfl_xor(Sxx, 32, 64);
    Sxy += __shfl_xor(Sxy, 32, 64);
    Sxz += __shfl_xor(Sxz, 32, 64);
    Syy += __shfl_xor(Syy, 32, 64);
    Syz += __shfl_xor(Syz, 32, 64);
    Szz += __shfl_xor(Szz, 32, 64);

    // norm2 of I+A+S for feature f
    float M00 = sI + Sxx, M01 = -vA2 + Sxy, M02 = vA1 + Sxz;
    float M10 = vA2 + Sxy, M11 = sI + Syy, M12 = -vA0 + Syz;
    float M20 = -vA1 + Sxz, M21 = vA0 + Syz, M22 = sI + Szz;
    float norm2 = M00 * M00 + M01 * M01 + M02 * M02 + M10 * M10 + M11 * M11 +
                  M12 * M12 + M20 * M20 + M21 * M21 + M22 * M22;

    // LayerNorm over 32 features (each f present in both subs -> /64)
    float mu = norm2;
#pragma unroll
    for (int m = 32; m >= 1; m >>= 1) mu += __shfl_xor(mu, m, 64);
    mu *= (1.0f / 64.0f);
    float dd = norm2 - mu;
    float vv = dd * dd;
#pragma unroll
    for (int m = 32; m >= 1; m >>= 1) vv += __shfl_xor(vv, m, 64);
    vv *= (1.0f / 64.0f);
    float h = dd * rsqrtf(vv + 1e-5f) * ln_w[f] + ln_b[f];
    if (sub == 0) h_st[wave][f] = h;

    // MLP1: 64 outputs (same-wave LDS, lockstep-ordered)
    {
        float acc = b_s1[lane];
#pragma unroll
        for (int k = 0; k < 32; k++) acc += h_st[wave][k] * ws1t[k * 65 + lane];
        h1_st[wave][lane] = silu_f(acc);
    }

    // MLP2: 96 outputs
    {
        float acc = b_s2[lane];
        float acc2 = (lane < 32) ? b_s2[64 + lane] : 0.f;
#pragma unroll
        for (int k = 0; k < 64; k++) {
            float hk = h1_st[wave][k];
            acc += hk * ws2t[k * 97 + lane];
            if (lane < 32) acc2 += hk * ws2t[k * 97 + 64 + lane];
        }
        h2_st[wave][lane] = silu_f(acc);
        if (lane < 32) h2_st[wave][64 + lane] = silu_f(acc2);
    }

    // stage per-f tensor components
    if (sub == 0) {
        vals_st[wave][0 * 32 + f] = sI;
        vals_st[wave][1 * 32 + f] = vA0;
        vals_st[wave][2 * 32 + f] = vA1;
        vals_st[wave][3 * 32 + f] = vA2;
        vals_st[wave][4 * 32 + f] = Sxx;
        vals_st[wave][5 * 32 + f] = Sxy;
        vals_st[wave][6 * 32 + f] = Sxz;
        vals_st[wave][7 * 32 + f] = Syy;
        vals_st[wave][8 * 32 + f] = Syz;
        vals_st[wave][9 * 32 + f] = Szz;
    }

    // channel mixing + combine with s3; X staged back into vals_st
    {
        const int g = f;
        float mI = 0.f, mA0 = 0.f, mA1 = 0.f, mA2 = 0.f;
        float mSxx = 0.f, mSxy = 0.f, mSxz = 0.f, mSyy = 0.f, mSyz = 0.f, mSzz = 0.f;
        const float* V = vals_st[wave];
#pragma unroll 8
        for (int ff = 0; ff < 32; ff++) {
            float w0 = wt0t[ff * 33 + g];
            float w1 = wt1t[ff * 33 + g];
            float w2 = wt2t[ff * 33 + g];
            mI += w0 * V[ff];
            mA0 += w1 * V[32 + ff];
            mA1 += w1 * V[64 + ff];
            mA2 += w1 * V[96 + ff];
            mSxx += w2 * V[128 + ff];
            mSxy += w2 * V[160 + ff];
            mSxz += w2 * V[192 + ff];
            mSyy += w2 * V[224 + ff];
            mSyz += w2 * V[256 + ff];
            mSzz += w2 * V[288 + ff];
        }
        float s0 = h2_st[wave][g * 3 + 0];
        float s1 = h2_st[wave][g * 3 + 1];
        float s2 = h2_st[wave][g * 3 + 2];
        float* X = vals_st[wave];
        if (sub == 0) {
            X[g * 9 + 0] = s0 * mI + s2 * mSxx;
            X[g * 9 + 1] = -s1 * mA2 + s2 * mSxy;
            X[g * 9 + 2] = s1 * mA1 + s2 * mSxz;
            X[g * 9 + 3] = s1 * mA2 + s2 * mSxy;
            X[g * 9 + 4] = s0 * mI + s2 * mSyy;
        } else {
            X[g * 9 + 5] = -s1 * mA0 + s2 * mSyz;
            X[g * 9 + 6] = -s1 * mA1 + s2 * mSxz;
            X[g * 9 + 7] = s1 * mA0 + s2 * mSyz;
            X[g * 9 + 8] = s0 * mI + s2 * mSzz;
        }
    }

    // coalesced X write: 288 contiguous floats per atom
    {
        float* dst = out + (long)atom * 288;
        const float* xs = vals_st[wave];
#pragma unroll
        for (int c = 0; c < 5; c++) {
            int i = lane + c * 64;
            if (i < 288) dst[i] = xs[i];
        }
    }
}

extern "C" void kernel_launch(void* const* d_in, const int* in_sizes, int n_in,
                              void* d_out, int out_size, void* d_ws, size_t ws_size,
                              hipStream_t stream) {
    const int* anum = (const int*)d_in[0];
    const int* pidx = (const int*)d_in[1];
    const float* r_ij = (const float*)d_in[2];
    const float* d_ijp = (const float*)d_in[3];
    const float* emb = (const float*)d_in[4];
    const float* w_zij = (const float*)d_in[5];
    const float* b_zij = (const float*)d_in[6];
    const float* w_I = (const float*)d_in[7];
    const float* b_I = (const float*)d_in[8];
    const float* w_A = (const float*)d_in[9];
    const float* b_A = (const float*)d_in[10];
    const float* w_S = (const float*)d_in[11];
    const float* b_S = (const float*)d_in[12];
    const float* w_t0 = (const float*)d_in[13];
    const float* w_t1 = (const float*)d_in[14];
    const float* w_t2 = (const float*)d_in[15];
    const float* w_s1 = (const float*)d_in[16];
    const float* b_s1 = (const float*)d_in[17];
    const float* w_s2 = (const float*)d_in[18];
    const float* b_s2 = (const float*)d_in[19];
    const float* ln_w = (const float*)d_in[20];
    const float* ln_b = (const float*)d_in[21];
    float* out = (float*)d_out;

    // workspace layout (~88 MB), 16B-aligned where vector-loaded
    float* EW = (float*)d_ws;                                   // 6400 f
    int* counts = (int*)(EW + 6400);                            // 25000 i
    int* cursor = counts + NATOMS;                              // 25000 i
    int* offsets = cursor + NATOMS;                             // 25004 i (padded)
    int* qlist = offsets + NATOMS + 4;                          // 400000 i
    float* rhatS = (float*)(qlist + NPAIRS);                    // 1.6M f (16B-aligned)
    __half2* coefIA = (__half2*)(rhatS + (size_t)NPAIRS * 4);   // 12.8M half2
    __half* coefS = (__half*)(coefIA + (size_t)NPAIRS * 32);    // 12.8M half
    int* zpk = (int*)(coefS + (size_t)NPAIRS * 32);             // 400000 i

    hipMemsetAsync(counts, 0, 2 * NATOMS * sizeof(int), stream);  // counts + cursor
    k_ew<<<25, 256, 0, stream>>>(emb, w_zij, EW);
    k_count<<<(NPAIRS + 255) / 256, 256, 0, stream>>>(pidx, counts);
    k_scan<<<1, 1024, 0, stream>>>(counts, offsets);
    k_fill<<<(NPAIRS + 255) / 256, 256, 0, stream>>>(pidx, anum, offsets, cursor, qlist, zpk);
    k_rad<<<(NPAIRS * 32 + 255) / 256, 256, 0, stream>>>(d_ijp, out + XSIZE);
    k_pair<<<NPAIRS / 64, 256, 0, stream>>>(qlist, zpk, r_ij, d_ijp, EW, b_zij,
                                            w_I, b_I, w_A, b_A, w_S, b_S,
                                            coefIA, coefS, rhatS);
    k_atom2<<<NATOMS / WPB, 512, 0, stream>>>(coefIA, coefS, rhatS, offsets,
                                              w_t0, w_t1, w_t2, w_s1, b_s1,
                                              w_s2, b_s2, ln_w, ln_b, out);
}

// Round 4
// 449.646 us; speedup vs baseline: 1.4603x; 1.2620x over previous
//
#include <hip/hip_runtime.h>
#include <hip/hip_fp16.h>
#include <math.h>

#define NATOMS 25000
#define NPAIRS 400000
#define XSIZE (NATOMS * 32 * 9)   // 7,200,000 floats; radial output follows
#define TWO_PI 6.28318530717958647692f
#define WPB 16   // atoms (waves) per k_atom2 block

__device__ __forceinline__ float silu_f(float x) { return x / (1.0f + expf(-x)); }

// ---------------- K0: fused EW build (25 blocks) + pair counting ----------------
// EW[tab*3200 + z*32 + f]: tab 0 -> w_zij cols 0..31 (atom i), tab 1 -> cols 32..63 (atom j)
__global__ void k_cnt_ew(const int* __restrict__ pidx, int* __restrict__ counts,
                         const float* __restrict__ emb, const float* __restrict__ wz,
                         float* __restrict__ EW) {
    if (blockIdx.x < 25) {
        int t = blockIdx.x * 256 + threadIdx.x;
        if (t >= 2 * 100 * 32) return;
        int tab = t / 3200;
        int rem = t - tab * 3200;
        int z = rem >> 5;
        int f = rem & 31;
        const float* e = emb + z * 32;
        const float* w = wz + f * 64 + tab * 32;
        float acc = 0.f;
#pragma unroll
        for (int k = 0; k < 32; k++) acc += e[k] * w[k];
        EW[t] = acc;
    } else {
        int p = (blockIdx.x - 25) * 256 + threadIdx.x;
        if (p >= NPAIRS) return;
        atomicAdd(&counts[pidx[p]], 1);
    }
}

// ---------------- K1: exclusive scan of counts -> offsets (single block) ----------------
__global__ __launch_bounds__(1024) void k_scan(const int* __restrict__ counts,
                                               int* __restrict__ offsets) {
    __shared__ int part[1024];
    const int t = threadIdx.x;
    const int base = t * 25;  // 1024*25 = 25600 >= NATOMS
    int mysum = 0;
    for (int i = 0; i < 25; i++) {
        int idx = base + i;
        mysum += (idx < NATOMS) ? counts[idx] : 0;
    }
    part[t] = mysum;
    __syncthreads();
    for (int off = 1; off < 1024; off <<= 1) {
        int v = (t >= off) ? part[t - off] : 0;
        __syncthreads();
        part[t] += v;
        __syncthreads();
    }
    int excl = part[t] - mysum;
    for (int i = 0; i < 25; i++) {
        int idx = base + i;
        if (idx < NATOMS) {
            offsets[idx] = excl;
            excl += counts[idx];
        }
    }
    if (t == 1023) offsets[NATOMS] = part[1023];
}

// ---------------- K2: compact, atom-sorted per-slot records ----------------
// qz[slot] = (pair id, packed species); rd4[slot] = (d, rx, ry, rz).
__global__ void k_fill(const int* __restrict__ pidx, const int* __restrict__ anum,
                       const float* __restrict__ r_ij, const float* __restrict__ d_ij,
                       const int* __restrict__ offsets, int* __restrict__ cursor,
                       int2* __restrict__ qz, float4* __restrict__ rd4) {
    int p = blockIdx.x * 256 + threadIdx.x;
    if (p >= NPAIRS) return;
    int a = pidx[p];
    int aj = pidx[NPAIRS + p];
    int j = atomicAdd(&cursor[a], 1);
    int slot = offsets[a] + j;
    qz[slot] = make_int2(p, (anum[a] << 16) | anum[aj]);
    rd4[slot] = make_float4(d_ij[p], r_ij[3 * p], r_ij[3 * p + 1], r_ij[3 * p + 2]);
}

// ---------------- K3: slot-ordered coefficient kernel + radial output ----------------
// lane = (f 0..31, h 0..1); h is the K-HALF index (not the pair index).
// Each iteration the wave processes 2 pairs (A = even slot, B = odd slot):
//   - half h computes radial/rcut for ITS OWN pair (h==0 -> A, h==1 -> B)
//   - the radial matvec is K-split: lane (f,h) holds only 16 weights per matrix
//     (k in [16h,16h+16)) and accumulates partials for BOTH pairs; one
//     shfl_xor(32) per output combines halves. 48 weight VGPRs instead of 96
//     (rounds 2-3 spilled at 96 -> scratch traffic).
__global__ __launch_bounds__(256, 1) void k_pair(
    const int2* __restrict__ qz, const float4* __restrict__ rd4,
    const float* __restrict__ EW, const float* __restrict__ b_zij,
    const float* __restrict__ w_I, const float* __restrict__ b_I,
    const float* __restrict__ w_A, const float* __restrict__ b_A,
    const float* __restrict__ w_S, const float* __restrict__ b_S,
    __half2* __restrict__ coefIA, __half* __restrict__ coefS,
    float4* __restrict__ rhatS, float* __restrict__ out_rad) {
    __shared__ float ewl[6400];
    for (int i = threadIdx.x; i < 6400; i += 256) ewl[i] = EW[i];

    const int tid = threadIdx.x;
    const int lane = tid & 63;
    const int wave = tid >> 6;
    const int f = lane & 31;
    const int h = lane >> 5;          // k-half

    float wIr[16], wAr[16], wSr[16];
#pragma unroll
    for (int j = 0; j < 16; j++) {
        int k = h * 16 + j;
        wIr[j] = w_I[f * 32 + k];
        wAr[j] = w_A[f * 32 + k];
        wSr[j] = w_S[f * 32 + k];
    }
    const float bIv = b_I[f], bAv = b_A[f], bSv = b_S[f], bzv = b_zij[f];

    const float start = 0.006737946999085467f;          // exp(-5)
    const float step = (1.0f - start) * (1.0f / 31.0f);
    const float tmp = 0.0625f * (1.0f - start);
    const float bconst = 1.0f / (tmp * tmp);
    const float center = start + (float)f * step;

    __syncthreads();

    const int wave_base = (blockIdx.x * 4 + wave) * 16;
    const int2 qzv = qz[wave_base + (lane & 15)];  // 16 slots' records, lanes replicated

#pragma unroll
    for (int it = 0; it < 8; it++) {
        const int s_mine = wave_base + 2 * it + h;
        float4 rv = rd4[s_mine];                    // 2 broadcast lines per wave
        int p_mine = __shfl(qzv.x, 2 * it + h, 64);
        int z_mine = __shfl(qzv.y, 2 * it + h, 64);

        float d = rv.x;
        float invd = 1.0f / d;
        float hx = rv.y * invd, hy = rv.z * invd, hz = rv.w * invd;
        float rcut = (d < 0.5f) ? 0.5f * (cosf(d * TWO_PI) + 1.0f) : 0.0f;
        float ee = expf(-10.0f * d);
        float diff = ee - center;
        float radf = expf(-bconst * diff * diff) * rcut;
        out_rad[(long)p_mine * 32 + f] = radf;      // dense 128B chunk per half-wave

        // K-split matvec partials for both pairs (rad_k^A in lane k, ^B in lane 32+k)
        float pIA = 0.f, pAA = 0.f, pSA = 0.f, pIB = 0.f, pAB = 0.f, pSB = 0.f;
#pragma unroll
        for (int j = 0; j < 16; j++) {
            float rA = __shfl(radf, 16 * h + j, 64);
            float rB = __shfl(radf, 32 + 16 * h + j, 64);
            pIA += rA * wIr[j]; pAA += rA * wAr[j]; pSA += rA * wSr[j];
            pIB += rB * wIr[j]; pAB += rB * wAr[j]; pSB += rB * wSr[j];
        }
        float fIA = pIA + __shfl_xor(pIA, 32, 64) + bIv;
        float fAA = pAA + __shfl_xor(pAA, 32, 64) + bAv;
        float fSA = pSA + __shfl_xor(pSA, 32, 64) + bSv;
        float fIB = pIB + __shfl_xor(pIB, 32, 64) + bIv;
        float fAB = pAB + __shfl_xor(pAB, 32, 64) + bAv;
        float fSB = pSB + __shfl_xor(pSB, 32, 64) + bSv;

        float zf = ewl[(z_mine >> 16) * 32 + f] + ewl[3200 + (z_mine & 0xffff) * 32 + f] + bzv;
        float C = rcut * zf;                         // own pair's rcut
        float aI = (h ? fIB : fIA) * C;
        float aA = (h ? fAB : fAA) * C;
        float aS = (h ? fSB : fSA) * C;

        coefIA[(long)s_mine * 32 + f] = __floats2half2_rn(aI, aA);  // 128B per half
        coefS[(long)s_mine * 32 + f] = __float2half_rn(aS);
        if (f == 0) rhatS[s_mine] = make_float4(hx, hy, hz, 0.f);
    }
}

// ---------------- K4: atom-major sequential accumulate + fused epilogue ----------------
// 1024 threads = 16 waves = 16 atoms/block; epilogue LDS per-wave private (no
// barriers after weight staging). Coef reads sequential within the atom segment.
__global__ __launch_bounds__(1024) void k_atom2(
    const __half2* __restrict__ coefIA, const __half* __restrict__ coefS,
    const float4* __restrict__ rhatS, const int* __restrict__ offsets,
    const float* __restrict__ w_t0, const float* __restrict__ w_t1,
    const float* __restrict__ w_t2,
    const float* __restrict__ w_s1, const float* __restrict__ b_s1,
    const float* __restrict__ w_s2, const float* __restrict__ b_s2,
    const float* __restrict__ ln_w, const float* __restrict__ ln_b,
    float* __restrict__ out) {
    __shared__ float ws1t[32 * 65];
    __shared__ float ws2t[64 * 97];
    __shared__ float wt0t[32 * 33];
    __shared__ float wt1t[32 * 33];
    __shared__ float wt2t[32 * 33];
    __shared__ float h_st[WPB][32];
    __shared__ float h1_st[WPB][64];
    __shared__ float h2_st[WPB][96];
    __shared__ float vals_st[WPB][320];   // 10 comps x 32f; reused as X staging

    const int tid = threadIdx.x;
    for (int i = tid; i < 64 * 32; i += 1024) { int o = i >> 5, ff = i & 31; ws1t[ff * 65 + o] = w_s1[i]; }
    for (int i = tid; i < 96 * 64; i += 1024) { int o = i >> 6, k = i & 63; ws2t[k * 97 + o] = w_s2[i]; }
    for (int i = tid; i < 32 * 32; i += 1024) {
        int g = i >> 5, ff = i & 31;
        wt0t[ff * 33 + g] = w_t0[i];
        wt1t[ff * 33 + g] = w_t1[i];
        wt2t[ff * 33 + g] = w_t2[i];
    }
    __syncthreads();

    const int wave = tid >> 6;
    const int lane = tid & 63;
    const int f = lane & 31;
    const int sub = lane >> 5;
    const int atom = blockIdx.x * WPB + wave;
    if (atom >= NATOMS) return;   // per-wave exit; no cross-wave barriers below

    float sI = 0.f, vA0 = 0.f, vA1 = 0.f, vA2 = 0.f;
    float Sxx = 0.f, Sxy = 0.f, Sxz = 0.f, Syy = 0.f, Syz = 0.f, Szz = 0.f;

    const int start = offsets[atom];
    const int cnt = offsets[atom + 1] - start;

    for (int t0 = 0; t0 < cnt; t0 += 4) {
        const int idx0 = t0 + sub;
        const int idx1 = t0 + 2 + sub;
        const bool v0 = idx0 < cnt;
        const bool v1 = idx1 < cnt;
        const long s0 = start + (v0 ? idx0 : 0);
        const long s1 = start + (v1 ? idx1 : 0);
        // both slot-loads issued before use (2 in flight per sub)
        float2 ia0 = __half22float2(coefIA[s0 * 32 + f]);
        float aS0 = __half2float(coefS[s0 * 32 + f]);
        float4 rh0 = rhatS[s0];
        float2 ia1 = __half22float2(coefIA[s1 * 32 + f]);
        float aS1 = __half2float(coefS[s1 * 32 + f]);
        float4 rh1 = rhatS[s1];
        if (v0) {
            sI += ia0.x;
            vA0 += ia0.y * rh0.x; vA1 += ia0.y * rh0.y; vA2 += ia0.y * rh0.z;
            Sxx += aS0 * (rh0.x * rh0.x - (1.0f / 3.0f));
            Sxy += aS0 * (rh0.x * rh0.y);
            Sxz += aS0 * (rh0.x * rh0.z);
            Syy += aS0 * (rh0.y * rh0.y - (1.0f / 3.0f));
            Syz += aS0 * (rh0.y * rh0.z);
            Szz += aS0 * (rh0.z * rh0.z - (1.0f / 3.0f));
        }
        if (v1) {
            sI += ia1.x;
            vA0 += ia1.y * rh1.x; vA1 += ia1.y * rh1.y; vA2 += ia1.y * rh1.z;
            Sxx += aS1 * (rh1.x * rh1.x - (1.0f / 3.0f));
            Sxy += aS1 * (rh1.x * rh1.y);
            Sxz += aS1 * (rh1.x * rh1.z);
            Syy += aS1 * (rh1.y * rh1.y - (1.0f / 3.0f));
            Syz += aS1 * (rh1.y * rh1.z);
            Szz += aS1 * (rh1.z * rh1.z - (1.0f / 3.0f));
        }
    }
    // combine sub-halves
    sI += __shfl_xor(sI, 32, 64);
    vA0 += __shfl_xor(vA0, 32, 64);
    vA1 += __shfl_xor(vA1, 32, 64);
    vA2 += __shfl_xor(vA2, 32, 64);
    Sxx += __shfl_xor(Sxx, 32, 64);
    Sxy += __shfl_xor(Sxy, 32, 64);
    Sxz += __shfl_xor(Sxz, 32, 64);
    Syy += __shfl_xor(Syy, 32, 64);
    Syz += __shfl_xor(Syz, 32, 64);
    Szz += __shfl_xor(Szz, 32, 64);

    // norm2 of I+A+S for feature f
    float M00 = sI + Sxx, M01 = -vA2 + Sxy, M02 = vA1 + Sxz;
    float M10 = vA2 + Sxy, M11 = sI + Syy, M12 = -vA0 + Syz;
    float M20 = -vA1 + Sxz, M21 = vA0 + Syz, M22 = sI + Szz;
    float norm2 = M00 * M00 + M01 * M01 + M02 * M02 + M10 * M10 + M11 * M11 +
                  M12 * M12 + M20 * M20 + M21 * M21 + M22 * M22;

    // LayerNorm over 32 features (each f present in both subs -> /64)
    float mu = norm2;
#pragma unroll
    for (int m = 32; m >= 1; m >>= 1) mu += __shfl_xor(mu, m, 64);
    mu *= (1.0f / 64.0f);
    float dd = norm2 - mu;
    float vv = dd * dd;
#pragma unroll
    for (int m = 32; m >= 1; m >>= 1) vv += __shfl_xor(vv, m, 64);
    vv *= (1.0f / 64.0f);
    float h = dd * rsqrtf(vv + 1e-5f) * ln_w[f] + ln_b[f];
    if (sub == 0) h_st[wave][f] = h;

    // MLP1: 64 outputs (same-wave LDS, lockstep-ordered)
    {
        float acc = b_s1[lane];
#pragma unroll
        for (int k = 0; k < 32; k++) acc += h_st[wave][k] * ws1t[k * 65 + lane];
        h1_st[wave][lane] = silu_f(acc);
    }

    // MLP2: 96 outputs
    {
        float acc = b_s2[lane];
        float acc2 = (lane < 32) ? b_s2[64 + lane] : 0.f;
#pragma unroll
        for (int k = 0; k < 64; k++) {
            float hk = h1_st[wave][k];
            acc += hk * ws2t[k * 97 + lane];
            if (lane < 32) acc2 += hk * ws2t[k * 97 + 64 + lane];
        }
        h2_st[wave][lane] = silu_f(acc);
        if (lane < 32) h2_st[wave][64 + lane] = silu_f(acc2);
    }

    // stage per-f tensor components
    if (sub == 0) {
        vals_st[wave][0 * 32 + f] = sI;
        vals_st[wave][1 * 32 + f] = vA0;
        vals_st[wave][2 * 32 + f] = vA1;
        vals_st[wave][3 * 32 + f] = vA2;
        vals_st[wave][4 * 32 + f] = Sxx;
        vals_st[wave][5 * 32 + f] = Sxy;
        vals_st[wave][6 * 32 + f] = Sxz;
        vals_st[wave][7 * 32 + f] = Syy;
        vals_st[wave][8 * 32 + f] = Syz;
        vals_st[wave][9 * 32 + f] = Szz;
    }

    // channel mixing + combine with s3; X staged back into vals_st
    {
        const int g = f;
        float mI = 0.f, mA0 = 0.f, mA1 = 0.f, mA2 = 0.f;
        float mSxx = 0.f, mSxy = 0.f, mSxz = 0.f, mSyy = 0.f, mSyz = 0.f, mSzz = 0.f;
        const float* V = vals_st[wave];
#pragma unroll 8
        for (int ff = 0; ff < 32; ff++) {
            float w0 = wt0t[ff * 33 + g];
            float w1 = wt1t[ff * 33 + g];
            float w2 = wt2t[ff * 33 + g];
            mI += w0 * V[ff];
            mA0 += w1 * V[32 + ff];
            mA1 += w1 * V[64 + ff];
            mA2 += w1 * V[96 + ff];
            mSxx += w2 * V[128 + ff];
            mSxy += w2 * V[160 + ff];
            mSxz += w2 * V[192 + ff];
            mSyy += w2 * V[224 + ff];
            mSyz += w2 * V[256 + ff];
            mSzz += w2 * V[288 + ff];
        }
        float s0 = h2_st[wave][g * 3 + 0];
        float s1 = h2_st[wave][g * 3 + 1];
        float s2 = h2_st[wave][g * 3 + 2];
        float* X = vals_st[wave];
        if (sub == 0) {
            X[g * 9 + 0] = s0 * mI + s2 * mSxx;
            X[g * 9 + 1] = -s1 * mA2 + s2 * mSxy;
            X[g * 9 + 2] = s1 * mA1 + s2 * mSxz;
            X[g * 9 + 3] = s1 * mA2 + s2 * mSxy;
            X[g * 9 + 4] = s0 * mI + s2 * mSyy;
        } else {
            X[g * 9 + 5] = -s1 * mA0 + s2 * mSyz;
            X[g * 9 + 6] = -s1 * mA1 + s2 * mSxz;
            X[g * 9 + 7] = s1 * mA0 + s2 * mSyz;
            X[g * 9 + 8] = s0 * mI + s2 * mSzz;
        }
    }

    // coalesced X write: 288 contiguous floats per atom
    {
        float* dst = out + (long)atom * 288;
        const float* xs = vals_st[wave];
#pragma unroll
        for (int c = 0; c < 5; c++) {
            int i = lane + c * 64;
            if (i < 288) dst[i] = xs[i];
        }
    }
}

extern "C" void kernel_launch(void* const* d_in, const int* in_sizes, int n_in,
                              void* d_out, int out_size, void* d_ws, size_t ws_size,
                              hipStream_t stream) {
    const int* anum = (const int*)d_in[0];
    const int* pidx = (const int*)d_in[1];
    const float* r_ij = (const float*)d_in[2];
    const float* d_ijp = (const float*)d_in[3];
    const float* emb = (const float*)d_in[4];
    const float* w_zij = (const float*)d_in[5];
    const float* b_zij = (const float*)d_in[6];
    const float* w_I = (const float*)d_in[7];
    const float* b_I = (const float*)d_in[8];
    const float* w_A = (const float*)d_in[9];
    const float* b_A = (const float*)d_in[10];
    const float* w_S = (const float*)d_in[11];
    const float* b_S = (const float*)d_in[12];
    const float* w_t0 = (const float*)d_in[13];
    const float* w_t1 = (const float*)d_in[14];
    const float* w_t2 = (const float*)d_in[15];
    const float* w_s1 = (const float*)d_in[16];
    const float* b_s1 = (const float*)d_in[17];
    const float* w_s2 = (const float*)d_in[18];
    const float* b_s2 = (const float*)d_in[19];
    const float* ln_w = (const float*)d_in[20];
    const float* ln_b = (const float*)d_in[21];
    float* out = (float*)d_out;

    // workspace layout (~87 MB), 16B-aligned where vector-loaded
    float* EW = (float*)d_ws;                                   // 6400 f
    int* counts = (int*)(EW + 6400);                            // 25000 i
    int* cursor = counts + NATOMS;                              // 25000 i
    int* offsets = cursor + NATOMS;                             // 25002 i (+pad to even)
    float4* rd4 = (float4*)(offsets + NATOMS + 2);              // 400000 float4 (16B-aligned)
    int2* qz = (int2*)(rd4 + NPAIRS);                           // 400000 int2
    float4* rhatS = (float4*)(qz + NPAIRS);                     // 400000 float4
    __half2* coefIA = (__half2*)(rhatS + NPAIRS);               // 12.8M half2
    __half* coefS = (__half*)(coefIA + (size_t)NPAIRS * 32);    // 12.8M half

    hipMemsetAsync(counts, 0, 2 * NATOMS * sizeof(int), stream);  // counts + cursor
    k_cnt_ew<<<25 + (NPAIRS + 255) / 256, 256, 0, stream>>>(pidx, counts, emb, w_zij, EW);
    k_scan<<<1, 1024, 0, stream>>>(counts, offsets);
    k_fill<<<(NPAIRS + 255) / 256, 256, 0, stream>>>(pidx, anum, r_ij, d_ijp,
                                                     offsets, cursor, qz, rd4);
    k_pair<<<NPAIRS / 64, 256, 0, stream>>>(qz, rd4, EW, b_zij,
                                            w_I, b_I, w_A, b_A, w_S, b_S,
                                            coefIA, coefS, rhatS, out + XSIZE);
    k_atom2<<<(NATOMS + WPB - 1) / WPB, 1024, 0, stream>>>(coefIA, coefS, rhatS, offsets,
                                                           w_t0, w_t1, w_t2, w_s1, b_s1,
                                                           w_s2, b_s2, ln_w, ln_b, out);
}